// Round 4
// baseline (985.408 us; speedup 1.0000x reference)
//
#include <hip/hip_runtime.h>
#include <stdint.h>

// Problem constants
#define TS 64
#define BATCH 1024
#define HID 256
#define IMGD 2048

typedef __bf16 bf16_t;
typedef bf16_t bf16x8 __attribute__((ext_vector_type(8)));
typedef float f32x4 __attribute__((ext_vector_type(4)));

union U64F2 {
    unsigned long long u[2];
    bf16x8 v;
};

// load 8 consecutive fp32 (16B-aligned) and convert to a bf16x8 MFMA fragment
static __device__ __forceinline__ bf16x8 cvt8(const float* __restrict__ p) {
    const f32x4 a = *reinterpret_cast<const f32x4*>(p);
    const f32x4 b = *reinterpret_cast<const f32x4*>(p + 4);
    bf16x8 r;
    r[0] = (bf16_t)a[0]; r[1] = (bf16_t)a[1]; r[2] = (bf16_t)a[2]; r[3] = (bf16_t)a[3];
    r[4] = (bf16_t)b[0]; r[5] = (bf16_t)b[1]; r[6] = (bf16_t)b[2]; r[7] = (bf16_t)b[3];
    return r;
}
static __device__ __forceinline__ uint16_t f2bf(float f) {
    union { float f; uint32_t i; } c; c.f = f;
    uint32_t i = c.i;
    i += 0x7fffu + ((i >> 16) & 1u);   // RNE
    return (uint16_t)(i >> 16);
}
static __device__ __forceinline__ float sigm(float x) { return 1.f / (1.f + __expf(-x)); }
static __device__ __forceinline__ float tanh_f(float x) { return 1.f - 2.f / (1.f + __expf(2.f * x)); }

// two relaxed agent-scope u64 atomic loads -> one bf16x8 fragment
static __device__ __forceinline__ bf16x8 ld_h16(const unsigned long long* p) {
    U64F2 f;
    f.u[0] = __hip_atomic_load(p,     __ATOMIC_RELAXED, __HIP_MEMORY_SCOPE_AGENT);
    f.u[1] = __hip_atomic_load(p + 1, __ATOMIC_RELAXED, __HIP_MEMORY_SCOPE_AGENT);
    return f.v;
}

// ---------------------------------------------------------------------------
// Single persistent kernel: img-Linear+ReLU prologue + Embedding + LSTM +
// broadcast-add. 256 blocks x 256 threads. Block (g = blk&63, ch = blk>>6):
// owns batch rows [16g,16g+16) and hidden units [64ch,64ch+64).
//
// MFMA orientation: W = A operand (m = gate-row), x/h = B operand (n = batch).
// D[m=quad*4+r -> unit uw+quad*4+r][n=lane&15 -> batch b0+j]: each lane owns
// 4 CONSECUTIVE units x 1 batch row -> h publish is ONE u64 atomic store
// straight from registers (no LDS), out is a coalesced f32x4 store.
//
// Sync per step: publish u64 h stores -> __syncthreads (drains each wave's
// vmcnt before s_barrier, so all h stores are performed at the coherence
// point) -> thread0 plain relaxed atomic store flag=t+1 (single writer, no
// RMW, no fence -> no L2 writeback storms). Consumer spins on 3 peer flags;
// its own chunk needs no flag (ordered by its own barrier) and is loaded
// before the spin.
// ---------------------------------------------------------------------------
__global__ __launch_bounds__(256, 1) void lstm_kernel(
    const float* __restrict__ img_feature, const int* __restrict__ caption,
    const float* __restrict__ W_img, const float* __restrict__ b_img,
    const float* __restrict__ emb,
    const float* __restrict__ W_ih, const float* __restrict__ W_hh,
    const float* __restrict__ b_ih, const float* __restrict__ b_hh,
    unsigned long long* __restrict__ h_buf64,
    unsigned* __restrict__ ctr, float* __restrict__ out)
{
    const int g = blockIdx.x & 63, ch = blockIdx.x >> 6;
    const int b0 = g * 16, u0 = ch * 64;
    const int w = threadIdx.x >> 6, lane = threadIdx.x & 63;
    const int quad = lane >> 4, j = lane & 15;
    const int uw = u0 + w * 16;          // wave's first unit (16-unit tile)
    const int ulane = uw + quad * 4;     // this lane's first unit (owns 4)
    const int brow = b0 + j;             // this lane's batch row
    unsigned* flags = ctr + g * 16;      // 4 flags in one 64B line per group

    // ---- persistent weight A-fragments: m=lane&15=j -> gate row q*HID+uw+j
    bf16x8 Aih[4][8], Ahh[4][8];
#pragma unroll
    for (int q = 0; q < 4; ++q) {
        const int r = q * HID + uw + j;
        const float* pih = W_ih + (size_t)r * HID + quad * 8;
        const float* phh = W_hh + (size_t)r * HID + quad * 8;
#pragma unroll
        for (int kk = 0; kk < 8; ++kk) {
            Aih[q][kk] = cvt8(pih + kk * 32);
            Ahh[q][kk] = cvt8(phh + kk * 32);
        }
    }
    f32x4 biasv[4];
#pragma unroll
    for (int q = 0; q < 4; ++q)
#pragma unroll
        for (int r = 0; r < 4; ++r)
            biasv[q][r] = b_ih[q * HID + ulane + r] + b_hh[q * HID + ulane + r];

    // ---- img prologue: imgv[r] = relu(img_feature[brow] . W_img[ulane+r] + b)
    float imgv[4];
    {
        f32x4 D = {};
        const float* aw = W_img + (size_t)(uw + j) * IMGD + quad * 8;
        const float* bx = img_feature + (size_t)brow * IMGD + quad * 8;
        for (int kk = 0; kk < 64; ++kk) {
            bf16x8 a = cvt8(aw + kk * 32);
            bf16x8 b = cvt8(bx + kk * 32);
            D = __builtin_amdgcn_mfma_f32_16x16x32_bf16(a, b, D, 0, 0, 0);
        }
#pragma unroll
        for (int r = 0; r < 4; ++r) {
            float v = D[r] + b_img[ulane + r];
            imgv[r] = v > 0.f ? v : 0.f;
        }
    }

    float cst[4] = {0.f, 0.f, 0.f, 0.f};

    // ---- x B-fragments for t=0: n=j -> batch brow, k=kk*32+quad*8
    bf16x8 Bx[8], Bxn[8];
    {
        int cap = caption[brow];
        const float* px = emb + (size_t)cap * HID + quad * 8;
#pragma unroll
        for (int kk = 0; kk < 8; ++kk) Bx[kk] = cvt8(px + kk * 32);
    }

    const int p0 = (ch + 1) & 3, p1 = (ch + 2) & 3, p2 = (ch + 3) & 3;

    for (int t = 0; t < TS; ++t) {
        f32x4 C[4];
#pragma unroll
        for (int q = 0; q < 4; ++q) C[q] = biasv[q];

        // x_t part: independent of h, runs before any waiting
#pragma unroll
        for (int kk = 0; kk < 8; ++kk) {
#pragma unroll
            for (int q = 0; q < 4; ++q)
                C[q] = __builtin_amdgcn_mfma_f32_16x16x32_bf16(Aih[q][kk], Bx[kk], C[q], 0, 0, 0);
        }

        // prefetch next step's embedding row (overlaps spin + h-MFMA)
        {
            int tn = (t + 1 < TS) ? t + 1 : t;
            int cap = caption[tn * BATCH + brow];
            const float* px = emb + (size_t)cap * HID + quad * 8;
#pragma unroll
            for (int kk = 0; kk < 8; ++kk) Bxn[kk] = cvt8(px + kk * 32);
        }

        if (t > 0) {
            const unsigned long long* hb = h_buf64 + (size_t)((t - 1) & 1) * (BATCH * HID / 4);
            const unsigned long long* hrow = hb + (((size_t)brow * HID) >> 2);

            // self chunk: ordered by our own previous barrier, no flag needed
            bf16x8 Hs0 = ld_h16(hrow + ((ch * 64 +  0 + quad * 8) >> 2));
            bf16x8 Hs1 = ld_h16(hrow + ((ch * 64 + 32 + quad * 8) >> 2));

            // wait for the 3 peer chunks of h(t-1)
            const unsigned tgt = (unsigned)t;
            unsigned f0, f1, f2;
            do {
                f0 = __hip_atomic_load(flags + p0, __ATOMIC_RELAXED, __HIP_MEMORY_SCOPE_AGENT);
                f1 = __hip_atomic_load(flags + p1, __ATOMIC_RELAXED, __HIP_MEMORY_SCOPE_AGENT);
                f2 = __hip_atomic_load(flags + p2, __ATOMIC_RELAXED, __HIP_MEMORY_SCOPE_AGENT);
            } while (f0 < tgt || f1 < tgt || f2 < tgt);

            bf16x8 Hp[6];
#pragma unroll
            for (int pi = 0; pi < 3; ++pi) {
                int c = (ch + 1 + pi) & 3;
                Hp[pi * 2 + 0] = ld_h16(hrow + ((c * 64 +  0 + quad * 8) >> 2));
                Hp[pi * 2 + 1] = ld_h16(hrow + ((c * 64 + 32 + quad * 8) >> 2));
            }

            // h-MFMA: self first (loads already landed), then peers
#pragma unroll
            for (int q = 0; q < 4; ++q) {
                C[q] = __builtin_amdgcn_mfma_f32_16x16x32_bf16(Ahh[q][ch * 2 + 0], Hs0, C[q], 0, 0, 0);
                C[q] = __builtin_amdgcn_mfma_f32_16x16x32_bf16(Ahh[q][ch * 2 + 1], Hs1, C[q], 0, 0, 0);
            }
#pragma unroll
            for (int pi = 0; pi < 3; ++pi) {
                int c = (ch + 1 + pi) & 3;
#pragma unroll
                for (int q = 0; q < 4; ++q) {
                    C[q] = __builtin_amdgcn_mfma_f32_16x16x32_bf16(Ahh[q][c * 2 + 0], Hp[pi * 2 + 0], C[q], 0, 0, 0);
                    C[q] = __builtin_amdgcn_mfma_f32_16x16x32_bf16(Ahh[q][c * 2 + 1], Hp[pi * 2 + 1], C[q], 0, 0, 0);
                }
            }
        }

        // LSTM cell: lane holds 4 consecutive units x 1 batch row
        float hval[4];
        unsigned long long hpack = 0;
#pragma unroll
        for (int r = 0; r < 4; ++r) {
            float ig = sigm(C[0][r]);
            float fg = sigm(C[1][r]);
            float gg = tanh_f(C[2][r]);
            float og = sigm(C[3][r]);
            float c = fg * cst[r] + ig * gg;
            cst[r] = c;
            float h = og * tanh_f(c);
            hval[r] = h;
            hpack |= ((unsigned long long)f2bf(h)) << (16 * r);
        }

        // publish h(t): one relaxed agent-scope u64 atomic store from registers
        {
            unsigned long long* hw = h_buf64 + (size_t)(t & 1) * (BATCH * HID / 4);
            __hip_atomic_store(hw + (((size_t)brow * HID + ulane) >> 2), hpack,
                               __ATOMIC_RELAXED, __HIP_MEMORY_SCOPE_AGENT);
        }

        __syncthreads();   // every wave drains vmcnt -> all h stores performed
        if (threadIdx.x == 0)
            __hip_atomic_store(flags + ch, (unsigned)(t + 1),
                               __ATOMIC_RELAXED, __HIP_MEMORY_SCOPE_AGENT);

        // out store: coalesced f32x4, off the critical path
        {
            f32x4 o;
#pragma unroll
            for (int r = 0; r < 4; ++r) o[r] = hval[r] + imgv[r];
            *reinterpret_cast<f32x4*>(out + ((size_t)t * BATCH + brow) * HID + ulane) = o;
        }

#pragma unroll
        for (int kk = 0; kk < 8; ++kk) Bx[kk] = Bxn[kk];
    }
}

// ---------------------------------------------------------------------------
extern "C" void kernel_launch(void* const* d_in, const int* in_sizes, int n_in,
                              void* d_out, int out_size, void* d_ws, size_t ws_size,
                              hipStream_t stream) {
    const float* img_feature = (const float*)d_in[0];   // [1024, 2048] fp32
    const int*   caption     = (const int*)d_in[1];     // [64, 1024] int32
    const float* W_img       = (const float*)d_in[2];   // [256, 2048] fp32
    const float* b_img       = (const float*)d_in[3];   // [256] fp32
    const float* emb         = (const float*)d_in[4];   // [32000, 256] fp32
    const float* W_ih        = (const float*)d_in[5];   // [1024, 256] fp32
    const float* W_hh        = (const float*)d_in[6];   // [1024, 256] fp32
    const float* b_ih        = (const float*)d_in[7];   // [1024] fp32
    const float* b_hh        = (const float*)d_in[8];   // [1024] fp32
    float* out = (float*)d_out;                         // [64,1024,256] fp32

    uint8_t* ws = (uint8_t*)d_ws;
    unsigned* ctr = (unsigned*)ws;                                  // 64 groups * 64B = 4KB
    unsigned long long* h_buf64 = (unsigned long long*)(ws + 4096); // 2 x 512KB bf16 h

    // ws is poisoned 0xAA before every timed launch: zero the sync flags
    hipMemsetAsync(ctr, 0, 4096, stream);

    lstm_kernel<<<256, 256, 0, stream>>>(img_feature, caption, W_img, b_img, emb,
                                         W_ih, W_hh, b_ih, b_hh, h_buf64, ctr, out);
}

// Round 5
// 529.132 us; speedup vs baseline: 1.8623x; 1.8623x over previous
//
#include <hip/hip_runtime.h>
#include <stdint.h>

// Problem constants
#define TS 64
#define BATCH 1024
#define HID 256
#define IMGD 2048

typedef __bf16 bf16_t;
typedef bf16_t bf16x8 __attribute__((ext_vector_type(8)));
typedef float f32x4 __attribute__((ext_vector_type(4)));

union U64F2 {
    unsigned long long u[2];
    bf16x8 v;
};

// load 8 consecutive fp32 (16B-aligned) and convert to a bf16x8 MFMA fragment
static __device__ __forceinline__ bf16x8 cvt8(const float* __restrict__ p) {
    const f32x4 a = *reinterpret_cast<const f32x4*>(p);
    const f32x4 b = *reinterpret_cast<const f32x4*>(p + 4);
    bf16x8 r;
    r[0] = (bf16_t)a[0]; r[1] = (bf16_t)a[1]; r[2] = (bf16_t)a[2]; r[3] = (bf16_t)a[3];
    r[4] = (bf16_t)b[0]; r[5] = (bf16_t)b[1]; r[6] = (bf16_t)b[2]; r[7] = (bf16_t)b[3];
    return r;
}
static __device__ __forceinline__ uint16_t f2bf(float f) {
    union { float f; uint32_t i; } c; c.f = f;
    uint32_t i = c.i;
    i += 0x7fffu + ((i >> 16) & 1u);   // RNE
    return (uint16_t)(i >> 16);
}
static __device__ __forceinline__ float sigm(float x) { return 1.f / (1.f + __expf(-x)); }
static __device__ __forceinline__ float tanh_f(float x) { return 1.f - 2.f / (1.f + __expf(2.f * x)); }

// two relaxed agent-scope u64 atomic loads -> one bf16x8 fragment
static __device__ __forceinline__ bf16x8 ld_h16(const unsigned long long* p) {
    U64F2 f;
    f.u[0] = __hip_atomic_load(p,     __ATOMIC_RELAXED, __HIP_MEMORY_SCOPE_AGENT);
    f.u[1] = __hip_atomic_load(p + 1, __ATOMIC_RELAXED, __HIP_MEMORY_SCOPE_AGENT);
    return f.v;
}

// ---------------------------------------------------------------------------
// Single persistent kernel: img-Linear+ReLU prologue + Embedding + LSTM +
// broadcast-add. 256 blocks x 256 threads. Block (g = blk&63, ch = blk>>6):
// owns batch rows [16g,16g+16) and hidden units [64ch,64ch+64).
//
// MFMA orientation: W = A operand (m = gate-row), x/h = B operand (n = batch).
// Lane owns 4 consecutive units x 1 batch row -> h publish is ONE u64 atomic
// store from registers; out is a coalesced f32x4 store.
//
// CRITICAL (round-4 lesson): all weight/h fragment array indices must be
// COMPILE-TIME constants. Runtime indexing (Ahh[q][ch*2]) demotes the arrays
// to scratch -> 790 MB of HBM refetch per launch (measured). All loops below
// are fully unrolled with static indices so Aih/Ahh live in AGPRs.
//
// Sync per step: u64 h stores -> __syncthreads (each wave drains vmcnt before
// s_barrier -> stores performed at coherence point) -> thread0 relaxed flag
// store (single writer, no RMW, no fences -> no L2 writeback storms).
// Consumer spins on the 3 peer flags only.
// ---------------------------------------------------------------------------
__global__ __launch_bounds__(256, 1) void lstm_kernel(
    const float* __restrict__ img_feature, const int* __restrict__ caption,
    const float* __restrict__ W_img, const float* __restrict__ b_img,
    const float* __restrict__ emb,
    const float* __restrict__ W_ih, const float* __restrict__ W_hh,
    const float* __restrict__ b_ih, const float* __restrict__ b_hh,
    unsigned long long* __restrict__ h_buf64,
    unsigned* __restrict__ ctr, float* __restrict__ out)
{
    const int g = blockIdx.x & 63, ch = blockIdx.x >> 6;
    const int b0 = g * 16, u0 = ch * 64;
    const int w = threadIdx.x >> 6, lane = threadIdx.x & 63;
    const int quad = lane >> 4, j = lane & 15;
    const int uw = u0 + w * 16;          // wave's first unit (16-unit tile)
    const int ulane = uw + quad * 4;     // this lane's first unit (owns 4)
    const int brow = b0 + j;             // this lane's batch row
    unsigned* flags = ctr + g * 16;      // 4 flags in one 64B line per group

    // ---- img prologue first (before persistent regs go live):
    // imgv[r] = relu(img_feature[brow] . W_img[ulane+r] + b_img[ulane+r])
    float imgv[4];
    {
        f32x4 D = {};
        const float* aw = W_img + (size_t)(uw + j) * IMGD + quad * 8;
        const float* bx = img_feature + (size_t)brow * IMGD + quad * 8;
        for (int kk = 0; kk < 64; ++kk) {
            bf16x8 a = cvt8(aw + kk * 32);
            bf16x8 b = cvt8(bx + kk * 32);
            D = __builtin_amdgcn_mfma_f32_16x16x32_bf16(a, b, D, 0, 0, 0);
        }
#pragma unroll
        for (int r = 0; r < 4; ++r) {
            float v = D[r] + b_img[ulane + r];
            imgv[r] = v > 0.f ? v : 0.f;
        }
    }

    // ---- persistent weight A-fragments: m=lane&15=j -> gate row q*HID+uw+j
    bf16x8 Aih[4][8], Ahh[4][8];
#pragma unroll
    for (int q = 0; q < 4; ++q) {
        const int r = q * HID + uw + j;
        const float* pih = W_ih + (size_t)r * HID + quad * 8;
        const float* phh = W_hh + (size_t)r * HID + quad * 8;
#pragma unroll
        for (int kk = 0; kk < 8; ++kk) {
            Aih[q][kk] = cvt8(pih + kk * 32);
            Ahh[q][kk] = cvt8(phh + kk * 32);
        }
    }
    f32x4 biasv[4];
#pragma unroll
    for (int q = 0; q < 4; ++q)
#pragma unroll
        for (int r = 0; r < 4; ++r)
            biasv[q][r] = b_ih[q * HID + ulane + r] + b_hh[q * HID + ulane + r];

    float cst[4] = {0.f, 0.f, 0.f, 0.f};

    // ---- x B-fragments for t=0: n=j -> batch brow, k=kk*32+quad*8
    bf16x8 Bx[8], Bxn[8];
    {
        int cap = caption[brow];
        const float* px = emb + (size_t)cap * HID + quad * 8;
#pragma unroll
        for (int kk = 0; kk < 8; ++kk) Bx[kk] = cvt8(px + kk * 32);
    }

    const int p0 = (ch + 1) & 3, p1 = (ch + 2) & 3, p2 = (ch + 3) & 3;

    for (int t = 0; t < TS; ++t) {
        f32x4 C[4];
#pragma unroll
        for (int q = 0; q < 4; ++q) C[q] = biasv[q];

        // x_t part: independent of h, runs before any waiting
#pragma unroll
        for (int kk = 0; kk < 8; ++kk) {
#pragma unroll
            for (int q = 0; q < 4; ++q)
                C[q] = __builtin_amdgcn_mfma_f32_16x16x32_bf16(Aih[q][kk], Bx[kk], C[q], 0, 0, 0);
        }

        // prefetch next step's embedding row (overlaps spin + h-MFMA)
        {
            int tn = (t + 1 < TS) ? t + 1 : t;
            int cap = caption[tn * BATCH + brow];
            const float* px = emb + (size_t)cap * HID + quad * 8;
#pragma unroll
            for (int kk = 0; kk < 8; ++kk) Bxn[kk] = cvt8(px + kk * 32);
        }

        if (t > 0) {
            // wait for the 3 peer chunks of h(t-1); own chunk already ordered
            // by our previous barrier (and covered by our own flag == t)
            const unsigned tgt = (unsigned)t;
            unsigned f0, f1, f2;
            do {
                f0 = __hip_atomic_load(flags + p0, __ATOMIC_RELAXED, __HIP_MEMORY_SCOPE_AGENT);
                f1 = __hip_atomic_load(flags + p1, __ATOMIC_RELAXED, __HIP_MEMORY_SCOPE_AGENT);
                f2 = __hip_atomic_load(flags + p2, __ATOMIC_RELAXED, __HIP_MEMORY_SCOPE_AGENT);
            } while (f0 < tgt || f1 < tgt || f2 < tgt);

            const unsigned long long* hrow = h_buf64
                + (size_t)((t - 1) & 1) * (BATCH * HID / 4)
                + (((size_t)brow * HID) >> 2);

            // all 8 h fragments with STATIC offsets (kk*8 + quad*2 u64s)
            bf16x8 Hall[8];
#pragma unroll
            for (int kk = 0; kk < 8; ++kk)
                Hall[kk] = ld_h16(hrow + kk * 8 + quad * 2);

#pragma unroll
            for (int kk = 0; kk < 8; ++kk) {
#pragma unroll
                for (int q = 0; q < 4; ++q)
                    C[q] = __builtin_amdgcn_mfma_f32_16x16x32_bf16(Ahh[q][kk], Hall[kk], C[q], 0, 0, 0);
            }
        }

        // LSTM cell: lane holds 4 consecutive units x 1 batch row
        float hval[4];
        unsigned long long hpack = 0;
#pragma unroll
        for (int r = 0; r < 4; ++r) {
            float ig = sigm(C[0][r]);
            float fg = sigm(C[1][r]);
            float gg = tanh_f(C[2][r]);
            float og = sigm(C[3][r]);
            float c = fg * cst[r] + ig * gg;
            cst[r] = c;
            float h = og * tanh_f(c);
            hval[r] = h;
            hpack |= ((unsigned long long)f2bf(h)) << (16 * r);
        }

        // publish h(t): one relaxed agent-scope u64 atomic store from registers
        {
            unsigned long long* hw = h_buf64 + (size_t)(t & 1) * (BATCH * HID / 4);
            __hip_atomic_store(hw + (((size_t)brow * HID + ulane) >> 2), hpack,
                               __ATOMIC_RELAXED, __HIP_MEMORY_SCOPE_AGENT);
        }

        __syncthreads();   // every wave drains vmcnt -> all h stores performed
        if (threadIdx.x == 0)
            __hip_atomic_store(flags + ch, (unsigned)(t + 1),
                               __ATOMIC_RELAXED, __HIP_MEMORY_SCOPE_AGENT);

        // out store: coalesced f32x4, off the critical path
        {
            f32x4 o;
#pragma unroll
            for (int r = 0; r < 4; ++r) o[r] = hval[r] + imgv[r];
            *reinterpret_cast<f32x4*>(out + ((size_t)t * BATCH + brow) * HID + ulane) = o;
        }

#pragma unroll
        for (int kk = 0; kk < 8; ++kk) Bx[kk] = Bxn[kk];
    }
}

// ---------------------------------------------------------------------------
extern "C" void kernel_launch(void* const* d_in, const int* in_sizes, int n_in,
                              void* d_out, int out_size, void* d_ws, size_t ws_size,
                              hipStream_t stream) {
    const float* img_feature = (const float*)d_in[0];   // [1024, 2048] fp32
    const int*   caption     = (const int*)d_in[1];     // [64, 1024] int32
    const float* W_img       = (const float*)d_in[2];   // [256, 2048] fp32
    const float* b_img       = (const float*)d_in[3];   // [256] fp32
    const float* emb         = (const float*)d_in[4];   // [32000, 256] fp32
    const float* W_ih        = (const float*)d_in[5];   // [1024, 256] fp32
    const float* W_hh        = (const float*)d_in[6];   // [1024, 256] fp32
    const float* b_ih        = (const float*)d_in[7];   // [1024] fp32
    const float* b_hh        = (const float*)d_in[8];   // [1024] fp32
    float* out = (float*)d_out;                         // [64,1024,256] fp32

    uint8_t* ws = (uint8_t*)d_ws;
    unsigned* ctr = (unsigned*)ws;                                  // 64 groups * 64B = 4KB
    unsigned long long* h_buf64 = (unsigned long long*)(ws + 4096); // 2 x 512KB bf16 h

    // ws is poisoned 0xAA before every timed launch: zero the sync flags
    hipMemsetAsync(ctr, 0, 4096, stream);

    lstm_kernel<<<256, 256, 0, stream>>>(img_feature, caption, W_img, b_img, emb,
                                         W_ih, W_hh, b_ih, b_hh, h_buf64, ctr, out);
}